// Round 3
// baseline (169.016 us; speedup 1.0000x reference)
//
#include <hip/hip_runtime.h>

// ---------------------------------------------------------------------------
// Loss_17729624998144: bicubic-warp temporal loss.
// out = mean|ex*M1*(warp(in1)-prev)| + mean|msk*ex*(1-M1)*(warp(in2)-warp(fast))|
// msk = inside-grid AND NOT(4x4-maxpooled occlusion OR 2px border).
// msk==0 kills BOTH terms at a pixel -> early-out (vast majority of pixels for
// N(0,1) flow, but the full bicubic path is implemented for correctness).
//
// Structure: single fused kernel per 64x4 tile:
//   stage A: raw occlusion flags (7x67 halo) -> LDS   (~7.3 flow loads/pixel)
//   stage B: separable 4x4 max-pool (hpool in LDS, vpool in registers)
//   stage C: rare-path bicubic loss, block reduce -> partial[block]
// finalize kernel reduces the 8100 partials. No atomics, no zeroing pass.
// ---------------------------------------------------------------------------

constexpr int HH = 1080, WW = 1920;
constexpr int HW = HH * WW;
constexpr int TLX = 64, TLY = 4;          // tile = 64 x 4 pixels, 256 threads
constexpr int RAW_C = TLX + 3;            // 67 halo cols (x0-1 .. x0+65)
constexpr int RAW_R = TLY + 3;            // 7 halo rows  (y0-1 .. y0+5)
constexpr int NRAW = RAW_R * RAW_C;       // 469
constexpr int NHP = RAW_R * TLX;          // 448
constexpr int NBX = WW / TLX;             // 30 (exact)
constexpr int NBY = HH / TLY;             // 270 (exact)
constexpr int NB = NBX * NBY;             // 8100 blocks

__device__ __forceinline__ void cr_weights(float t, float w[4]) {
    float t2 = t * t, t3 = t2 * t;
    w[0] = 0.5f * (-t + 2.0f * t2 - t3);
    w[1] = 1.0f + 0.5f * (3.0f * t3 - 5.0f * t2);
    w[2] = 0.5f * (t + 4.0f * t2 - 3.0f * t3);
    w[3] = 0.5f * (t3 - t2);
}

__device__ __forceinline__ float bicubic4(const float* __restrict__ p,
                                          const float wx[4], const float wy[4]) {
    float s = 0.0f;
#pragma unroll
    for (int k = 0; k < 4; ++k) {
        const float* r = p + k * WW;
        float h = wx[0] * r[0];
        h = fmaf(wx[1], r[1], h);
        h = fmaf(wx[2], r[2], h);
        h = fmaf(wx[3], r[3], h);
        s = fmaf(wy[k], h, s);
    }
    return s;
}

__global__ __launch_bounds__(256) void fused_loss_kernel(
    const float* __restrict__ in1, const float* __restrict__ in2,
    const float* __restrict__ prev, const float* __restrict__ flow,
    const float* __restrict__ m10, const float* __restrict__ ex,
    const float* __restrict__ fast, float* __restrict__ partial) {
    __shared__ unsigned char raw[RAW_R][RAW_C + 5];  // pad to 72 (bank spread)
    __shared__ unsigned char hp[RAW_R][TLX];
    __shared__ float wsum[4];

    const int t = threadIdx.x;
    const int x0 = blockIdx.x * TLX;
    const int y0 = blockIdx.y * TLY;
    const float* __restrict__ f0 = flow;       // flow[0,0]
    const float* __restrict__ f1 = flow + HW;  // flow[0,1]

    // --- stage A: raw occlusion flags over the 7x67 halo region ---
    for (int e = t; e < NRAW; e += 256) {
        int rr = e / RAW_C, cc = e - rr * RAW_C;
        int yy = y0 - 1 + rr, xx = x0 - 1 + cc;
        int flag = 0;
        if (yy >= 0 && yy < HH && xx >= 0 && xx < WW) {
            float a = (yy < HH - 1) ? f0[(yy + 1) * WW + xx] - f0[yy * WW + xx] : 0.0f;
            float b = (xx < WW - 1) ? f1[yy * WW + xx + 1] - f1[yy * WW + xx] : 0.0f;
            flag = (fabsf(a + b) > 0.75f) ? 1 : 0;
        }
        raw[rr][cc] = (unsigned char)flag;
    }
    __syncthreads();

    // --- stage B1: horizontal 4-tap max (dx in -1..2) ---
    for (int e = t; e < NHP; e += 256) {
        int rr = e >> 6, cc = e & 63;
        hp[rr][cc] = raw[rr][cc] | raw[rr][cc + 1] | raw[rr][cc + 2] | raw[rr][cc + 3];
    }
    __syncthreads();

    // --- stage B2 + C: vertical 4-tap max, border, rare-path loss ---
    const int tx = t & 63, ty = t >> 6;
    const int x = x0 + tx, y = y0 + ty;
    int occ = hp[ty][tx] | hp[ty + 1][tx] | hp[ty + 2][tx] | hp[ty + 3][tx];
    if (y < 2 || y >= HH - 2 || x < 2 || x >= WW - 2) occ = 1;

    float local = 0.0f;
    if (!occ) {  // pixel survives occlusion+border mask (rare)
        int idx = y * WW + x;
        float fx = flow[idx];
        float fy = flow[HW + idx];
        float gx = (float)x + fx;
        float gy = (float)y + fy;
        float fgx = floorf(gx), fgy = floorf(gy);
        int bx0 = (int)fgx - 1;  // == floor(gx-1), exact
        int by0 = (int)fgy - 1;
        if (bx0 >= 0 && bx0 <= WW - 4 && by0 >= 0 && by0 <= HH - 4) {  // inside
            float txf = gx - fgx, tyf = gy - fgy;
            float wxw[4], wyw[4];
            cr_weights(txf, wxw);
            cr_weights(tyf, wyw);
            size_t base = (size_t)by0 * WW + bx0;
#pragma unroll
            for (int c = 0; c < 3; ++c) {
                size_t coff = (size_t)c * HW;
                float w1 = bicubic4(in1 + coff + base, wxw, wyw);
                float w2 = bicubic4(in2 + coff + base, wxw, wyw);
                float wf = bicubic4(fast + coff + base, wxw, wyw);
                float M = m10[coff + idx];  // msk==1 here
                float e = ex[coff + idx];
                local += fabsf(e * M * (w1 - prev[coff + idx]));
                local += fabsf(e * (1.0f - M) * (w2 - wf));
            }
        }
    }

    // --- block reduction: wave64 shuffle, then across the 4 waves ---
#pragma unroll
    for (int off = 32; off > 0; off >>= 1) local += __shfl_down(local, off, 64);
    int wid = t >> 6;
    if ((t & 63) == 0) wsum[wid] = local;
    __syncthreads();
    if (t == 0)
        partial[blockIdx.y * NBX + blockIdx.x] = wsum[0] + wsum[1] + wsum[2] + wsum[3];
}

__global__ __launch_bounds__(256) void reduce_kernel(
    const float* __restrict__ partial, float* __restrict__ out, double invN) {
    double s = 0.0;
    for (int i = threadIdx.x; i < NB; i += 256) s += (double)partial[i];
#pragma unroll
    for (int off = 32; off > 0; off >>= 1) s += __shfl_down(s, off, 64);
    __shared__ double wsum[4];
    int wid = threadIdx.x >> 6;
    if ((threadIdx.x & 63) == 0) wsum[wid] = s;
    __syncthreads();
    if (threadIdx.x == 0)
        out[0] = (float)((wsum[0] + wsum[1] + wsum[2] + wsum[3]) * invN);
}

extern "C" void kernel_launch(void* const* d_in, const int* in_sizes, int n_in,
                              void* d_out, int out_size, void* d_ws, size_t ws_size,
                              hipStream_t stream) {
    const float* in1  = (const float*)d_in[0];  // input1  (1,3,H,W)
    const float* in2  = (const float*)d_in[1];  // input2  (1,3,H,W)
    const float* prev = (const float*)d_in[2];  // prev_frame1 (3,H,W)
    const float* flow = (const float*)d_in[3];  // flow1   (1,2,H,W)
    const float* m10  = (const float*)d_in[4];  // mask1_0 (1,3,H,W)
    const float* ex   = (const float*)d_in[5];  // exclusive_mask1 (1,3,H,W)
    const float* fast = (const float*)d_in[6];  // fastdvdnet (1,3,H,W)
    float* out = (float*)d_out;

    float* partial = (float*)d_ws;  // NB floats; written unconditionally
    const double invN = 1.0 / (3.0 * (double)HW);  // both means over B*C*H*W

    dim3 grid(NBX, NBY);
    fused_loss_kernel<<<grid, 256, 0, stream>>>(in1, in2, prev, flow, m10, ex,
                                                fast, partial);
    reduce_kernel<<<1, 256, 0, stream>>>(partial, out, invN);
}

// Round 4
// 162.802 us; speedup vs baseline: 1.0382x; 1.0382x over previous
//
#include <hip/hip_runtime.h>

// ---------------------------------------------------------------------------
// Loss_17729624998144: bicubic-warp temporal loss.
// out = mean|ex*M1*(warp(in1)-prev)| + mean|msk*ex*(1-M1)*(warp(in2)-warp(fast))|
// msk = inside-grid AND NOT(4x4-maxpooled occlusion OR 2px border).
// msk==0 kills BOTH terms at a pixel -> early-out (vast majority of pixels for
// N(0,1) flow, but the full bicubic path is implemented for correctness).
//
// Structure: single fused kernel per 64x4 tile:
//   stage A: raw occlusion flags (7x67 halo) -> LDS   (~7.3 flow loads/pixel)
//   stage B: separable 4x4 max-pool (hpool in LDS, vpool in registers)
//   stage C: rare-path bicubic loss, block reduce -> partial[block]
// Round-4 change: reduce_kernel reads partials as float4 (8 independent 16B
// loads/thread) instead of 32 scalar strided loads — the round-3 regression
// was this single-block reduce being cross-XCD-latency-bound (~10 us).
// ---------------------------------------------------------------------------

constexpr int HH = 1080, WW = 1920;
constexpr int HW = HH * WW;
constexpr int TLX = 64, TLY = 4;          // tile = 64 x 4 pixels, 256 threads
constexpr int RAW_C = TLX + 3;            // 67 halo cols (x0-1 .. x0+65)
constexpr int RAW_R = TLY + 3;            // 7 halo rows  (y0-1 .. y0+5)
constexpr int NRAW = RAW_R * RAW_C;       // 469
constexpr int NHP = RAW_R * TLX;          // 448
constexpr int NBX = WW / TLX;             // 30 (exact)
constexpr int NBY = HH / TLY;             // 270 (exact)
constexpr int NB = NBX * NBY;             // 8100 blocks
constexpr int NB4 = NB / 4;               // 2025 float4s (8100 % 4 == 0)

__device__ __forceinline__ void cr_weights(float t, float w[4]) {
    float t2 = t * t, t3 = t2 * t;
    w[0] = 0.5f * (-t + 2.0f * t2 - t3);
    w[1] = 1.0f + 0.5f * (3.0f * t3 - 5.0f * t2);
    w[2] = 0.5f * (t + 4.0f * t2 - 3.0f * t3);
    w[3] = 0.5f * (t3 - t2);
}

__device__ __forceinline__ float bicubic4(const float* __restrict__ p,
                                          const float wx[4], const float wy[4]) {
    float s = 0.0f;
#pragma unroll
    for (int k = 0; k < 4; ++k) {
        const float* r = p + k * WW;
        float h = wx[0] * r[0];
        h = fmaf(wx[1], r[1], h);
        h = fmaf(wx[2], r[2], h);
        h = fmaf(wx[3], r[3], h);
        s = fmaf(wy[k], h, s);
    }
    return s;
}

__global__ __launch_bounds__(256) void fused_loss_kernel(
    const float* __restrict__ in1, const float* __restrict__ in2,
    const float* __restrict__ prev, const float* __restrict__ flow,
    const float* __restrict__ m10, const float* __restrict__ ex,
    const float* __restrict__ fast, float* __restrict__ partial) {
    __shared__ unsigned char raw[RAW_R][RAW_C + 5];  // pad to 72 (bank spread)
    __shared__ unsigned char hp[RAW_R][TLX];
    __shared__ float wsum[4];

    const int t = threadIdx.x;
    const int x0 = blockIdx.x * TLX;
    const int y0 = blockIdx.y * TLY;
    const float* __restrict__ f0 = flow;       // flow[0,0]
    const float* __restrict__ f1 = flow + HW;  // flow[0,1]

    // --- stage A: raw occlusion flags over the 7x67 halo region ---
    for (int e = t; e < NRAW; e += 256) {
        int rr = e / RAW_C, cc = e - rr * RAW_C;
        int yy = y0 - 1 + rr, xx = x0 - 1 + cc;
        int flag = 0;
        if (yy >= 0 && yy < HH && xx >= 0 && xx < WW) {
            float a = (yy < HH - 1) ? f0[(yy + 1) * WW + xx] - f0[yy * WW + xx] : 0.0f;
            float b = (xx < WW - 1) ? f1[yy * WW + xx + 1] - f1[yy * WW + xx] : 0.0f;
            flag = (fabsf(a + b) > 0.75f) ? 1 : 0;
        }
        raw[rr][cc] = (unsigned char)flag;
    }
    __syncthreads();

    // --- stage B1: horizontal 4-tap max (dx in -1..2) ---
    for (int e = t; e < NHP; e += 256) {
        int rr = e >> 6, cc = e & 63;
        hp[rr][cc] = raw[rr][cc] | raw[rr][cc + 1] | raw[rr][cc + 2] | raw[rr][cc + 3];
    }
    __syncthreads();

    // --- stage B2 + C: vertical 4-tap max, border, rare-path loss ---
    const int tx = t & 63, ty = t >> 6;
    const int x = x0 + tx, y = y0 + ty;
    int occ = hp[ty][tx] | hp[ty + 1][tx] | hp[ty + 2][tx] | hp[ty + 3][tx];
    if (y < 2 || y >= HH - 2 || x < 2 || x >= WW - 2) occ = 1;

    float local = 0.0f;
    if (!occ) {  // pixel survives occlusion+border mask (rare)
        int idx = y * WW + x;
        float fx = flow[idx];
        float fy = flow[HW + idx];
        float gx = (float)x + fx;
        float gy = (float)y + fy;
        float fgx = floorf(gx), fgy = floorf(gy);
        int bx0 = (int)fgx - 1;  // == floor(gx-1), exact
        int by0 = (int)fgy - 1;
        if (bx0 >= 0 && bx0 <= WW - 4 && by0 >= 0 && by0 <= HH - 4) {  // inside
            float txf = gx - fgx, tyf = gy - fgy;
            float wxw[4], wyw[4];
            cr_weights(txf, wxw);
            cr_weights(tyf, wyw);
            size_t base = (size_t)by0 * WW + bx0;
#pragma unroll
            for (int c = 0; c < 3; ++c) {
                size_t coff = (size_t)c * HW;
                float w1 = bicubic4(in1 + coff + base, wxw, wyw);
                float w2 = bicubic4(in2 + coff + base, wxw, wyw);
                float wf = bicubic4(fast + coff + base, wxw, wyw);
                float M = m10[coff + idx];  // msk==1 here
                float e = ex[coff + idx];
                local += fabsf(e * M * (w1 - prev[coff + idx]));
                local += fabsf(e * (1.0f - M) * (w2 - wf));
            }
        }
    }

    // --- block reduction: wave64 shuffle, then across the 4 waves ---
#pragma unroll
    for (int off = 32; off > 0; off >>= 1) local += __shfl_down(local, off, 64);
    int wid = t >> 6;
    if ((t & 63) == 0) wsum[wid] = local;
    __syncthreads();
    if (t == 0)
        partial[blockIdx.y * NBX + blockIdx.x] = wsum[0] + wsum[1] + wsum[2] + wsum[3];
}

__global__ __launch_bounds__(256) void reduce_kernel(
    const float* __restrict__ partial, float* __restrict__ out, double invN) {
    const float4* __restrict__ p4 = (const float4*)partial;
    double s = 0.0;
    // NB4 = 2025 float4s over 256 threads: <=8 independent 16B loads/thread
    for (int i = threadIdx.x; i < NB4; i += 256) {
        float4 v = p4[i];
        s += (double)((v.x + v.y) + (v.z + v.w));
    }
#pragma unroll
    for (int off = 32; off > 0; off >>= 1) s += __shfl_down(s, off, 64);
    __shared__ double wsum[4];
    int wid = threadIdx.x >> 6;
    if ((threadIdx.x & 63) == 0) wsum[wid] = s;
    __syncthreads();
    if (threadIdx.x == 0)
        out[0] = (float)((wsum[0] + wsum[1] + wsum[2] + wsum[3]) * invN);
}

extern "C" void kernel_launch(void* const* d_in, const int* in_sizes, int n_in,
                              void* d_out, int out_size, void* d_ws, size_t ws_size,
                              hipStream_t stream) {
    const float* in1  = (const float*)d_in[0];  // input1  (1,3,H,W)
    const float* in2  = (const float*)d_in[1];  // input2  (1,3,H,W)
    const float* prev = (const float*)d_in[2];  // prev_frame1 (3,H,W)
    const float* flow = (const float*)d_in[3];  // flow1   (1,2,H,W)
    const float* m10  = (const float*)d_in[4];  // mask1_0 (1,3,H,W)
    const float* ex   = (const float*)d_in[5];  // exclusive_mask1 (1,3,H,W)
    const float* fast = (const float*)d_in[6];  // fastdvdnet (1,3,H,W)
    float* out = (float*)d_out;

    float* partial = (float*)d_ws;  // NB floats; written unconditionally
    const double invN = 1.0 / (3.0 * (double)HW);  // both means over B*C*H*W

    dim3 grid(NBX, NBY);
    fused_loss_kernel<<<grid, 256, 0, stream>>>(in1, in2, prev, flow, m10, ex,
                                                fast, partial);
    reduce_kernel<<<1, 256, 0, stream>>>(partial, out, invN);
}

// Round 7
// 158.348 us; speedup vs baseline: 1.0674x; 1.0281x over previous
//
#include <hip/hip_runtime.h>

// ---------------------------------------------------------------------------
// Loss_17729624998144: bicubic-warp temporal loss.
// out = mean|ex*M1*(warp(in1)-prev)| + mean|msk*ex*(1-M1)*(warp(in2)-warp(fast))|
// msk = inside-grid AND NOT(4x4-maxpooled occlusion OR 2px border).
// msk==0 kills BOTH terms at a pixel -> early-out (vast majority of pixels for
// N(0,1) flow; full bicubic path implemented for correctness).
//
// Round-5 change: stage A vectorized — 4 occlusion flags per task from
// 3 float4 loads + 1 scalar (aligned), 126 tasks/tile (1 iter) vs 469 scalar
// tasks (2 iters, 1876 scalar loads). Pure issue-cost reduction; loads were
// already L1/L2 hits.
// ---------------------------------------------------------------------------

constexpr int HH = 1080, WW = 1920;
constexpr int HW = HH * WW;
constexpr int TLX = 64, TLY = 4;     // tile = 64 x 4 pixels, 256 threads
constexpr int RAW_R = TLY + 3;       // 7 halo rows (y0-1 .. y0+5)
constexpr int NGRP = 18;             // 18 aligned col groups of 4: x0-4 .. x0+67
constexpr int RAW_C = NGRP * 4;      // 72 stored flag cols
constexpr int NTASK = RAW_R * NGRP;  // 126 vec4 flag tasks
constexpr int NHP = RAW_R * TLX;     // 448
constexpr int NBX = WW / TLX;        // 30
constexpr int NBY = HH / TLY;        // 270
constexpr int NB = NBX * NBY;        // 8100
constexpr int NB4 = NB / 4;          // 2025

__device__ __forceinline__ void cr_weights(float t, float w[4]) {
    float t2 = t * t, t3 = t2 * t;
    w[0] = 0.5f * (-t + 2.0f * t2 - t3);
    w[1] = 1.0f + 0.5f * (3.0f * t3 - 5.0f * t2);
    w[2] = 0.5f * (t + 4.0f * t2 - 3.0f * t3);
    w[3] = 0.5f * (t3 - t2);
}

__device__ __forceinline__ float bicubic4(const float* __restrict__ p,
                                          const float wx[4], const float wy[4]) {
    float s = 0.0f;
#pragma unroll
    for (int k = 0; k < 4; ++k) {
        const float* r = p + k * WW;
        float h = wx[0] * r[0];
        h = fmaf(wx[1], r[1], h);
        h = fmaf(wx[2], r[2], h);
        h = fmaf(wx[3], r[3], h);
        s = fmaf(wy[k], h, s);
    }
    return s;
}

__global__ __launch_bounds__(256) void fused_loss_kernel(
    const float* __restrict__ in1, const float* __restrict__ in2,
    const float* __restrict__ prev, const float* __restrict__ flow,
    const float* __restrict__ m10, const float* __restrict__ ex,
    const float* __restrict__ fast, float* __restrict__ partial) {
    __shared__ unsigned char raw[RAW_R][RAW_C + 4];  // stride 76 (4-aligned)
    __shared__ unsigned char hp[RAW_R][TLX];
    __shared__ float wsum[4];

    const int t = threadIdx.x;
    const int x0 = blockIdx.x * TLX;
    const int y0 = blockIdx.y * TLY;
    const float* __restrict__ f0 = flow;       // flow[0,0]
    const float* __restrict__ f1 = flow + HW;  // flow[0,1]

    // --- stage A: occlusion flags, 4 per task, cols x0-4 .. x0+67 ---
    if (t < NTASK) {
        int rr = t / NGRP, g = t - rr * NGRP;
        int yy = y0 - 1 + rr;
        int xx0 = x0 - 4 + g * 4;  // float4-aligned
        uchar4 fl = make_uchar4(0, 0, 0, 0);
        if (yy >= 0 && yy < HH && xx0 >= 0 && xx0 <= WW - 4) {
            const float4 c0 = *(const float4*)(f0 + (size_t)yy * WW + xx0);
            float4 c1 = c0;
            if (yy < HH - 1) c1 = *(const float4*)(f0 + (size_t)(yy + 1) * WW + xx0);
            const float4 v1 = *(const float4*)(f1 + (size_t)yy * WW + xx0);
            const float v4 = (xx0 + 4 < WW) ? f1[(size_t)yy * WW + xx0 + 4] : 0.0f;
            const bool ha = (yy < HH - 1);
            float a0 = ha ? c1.x - c0.x : 0.0f;
            float a1 = ha ? c1.y - c0.y : 0.0f;
            float a2 = ha ? c1.z - c0.z : 0.0f;
            float a3 = ha ? c1.w - c0.w : 0.0f;
            float b0 = v1.y - v1.x;                              // xx0   < W-1 always
            float b1 = v1.z - v1.y;                              // xx0+1 < W-1 always
            float b2 = v1.w - v1.z;                              // xx0+2 < W-1 always
            float b3 = (xx0 + 3 < WW - 1) ? v4 - v1.w : 0.0f;    // xx0+3 == W-1 possible
            fl.x = fabsf(a0 + b0) > 0.75f;
            fl.y = fabsf(a1 + b1) > 0.75f;
            fl.z = fabsf(a2 + b2) > 0.75f;
            fl.w = fabsf(a3 + b3) > 0.75f;
        }
        *(uchar4*)&raw[rr][g * 4] = fl;
    }
    __syncthreads();

    // --- stage B1: horizontal 4-tap max; pixel x=x0+cc uses raw cols cc+3..cc+6 ---
    for (int e = t; e < NHP; e += 256) {
        int rr = e >> 6, cc = e & 63;
        hp[rr][cc] = raw[rr][cc + 3] | raw[rr][cc + 4] | raw[rr][cc + 5] | raw[rr][cc + 6];
    }
    __syncthreads();

    // --- stage B2 + C: vertical 4-tap max, border, rare-path loss ---
    const int tx = t & 63, ty = t >> 6;
    const int x = x0 + tx, y = y0 + ty;
    int occ = hp[ty][tx] | hp[ty + 1][tx] | hp[ty + 2][tx] | hp[ty + 3][tx];
    if (y < 2 || y >= HH - 2 || x < 2 || x >= WW - 2) occ = 1;

    float local = 0.0f;
    if (!occ) {  // pixel survives occlusion+border mask (rare)
        int idx = y * WW + x;
        float fx = flow[idx];
        float fy = flow[HW + idx];
        float gx = (float)x + fx;
        float gy = (float)y + fy;
        float fgx = floorf(gx), fgy = floorf(gy);
        int bx0 = (int)fgx - 1;  // == floor(gx-1), exact
        int by0 = (int)fgy - 1;
        if (bx0 >= 0 && bx0 <= WW - 4 && by0 >= 0 && by0 <= HH - 4) {  // inside
            float txf = gx - fgx, tyf = gy - fgy;
            float wxw[4], wyw[4];
            cr_weights(txf, wxw);
            cr_weights(tyf, wyw);
            size_t base = (size_t)by0 * WW + bx0;
#pragma unroll
            for (int c = 0; c < 3; ++c) {
                size_t coff = (size_t)c * HW;
                float w1 = bicubic4(in1 + coff + base, wxw, wyw);
                float w2 = bicubic4(in2 + coff + base, wxw, wyw);
                float wf = bicubic4(fast + coff + base, wxw, wyw);
                float M = m10[coff + idx];  // msk==1 here
                float e = ex[coff + idx];
                local += fabsf(e * M * (w1 - prev[coff + idx]));
                local += fabsf(e * (1.0f - M) * (w2 - wf));
            }
        }
    }

    // --- block reduction: wave64 shuffle, then across the 4 waves ---
#pragma unroll
    for (int off = 32; off > 0; off >>= 1) local += __shfl_down(local, off, 64);
    int wid = t >> 6;
    if ((t & 63) == 0) wsum[wid] = local;
    __syncthreads();
    if (t == 0)
        partial[blockIdx.y * NBX + blockIdx.x] = wsum[0] + wsum[1] + wsum[2] + wsum[3];
}

__global__ __launch_bounds__(256) void reduce_kernel(
    const float* __restrict__ partial, float* __restrict__ out, double invN) {
    const float4* __restrict__ p4 = (const float4*)partial;
    double s = 0.0;
    for (int i = threadIdx.x; i < NB4; i += 256) {
        float4 v = p4[i];
        s += (double)((v.x + v.y) + (v.z + v.w));
    }
#pragma unroll
    for (int off = 32; off > 0; off >>= 1) s += __shfl_down(s, off, 64);
    __shared__ double wsum[4];
    int wid = threadIdx.x >> 6;
    if ((threadIdx.x & 63) == 0) wsum[wid] = s;
    __syncthreads();
    if (threadIdx.x == 0)
        out[0] = (float)((wsum[0] + wsum[1] + wsum[2] + wsum[3]) * invN);
}

extern "C" void kernel_launch(void* const* d_in, const int* in_sizes, int n_in,
                              void* d_out, int out_size, void* d_ws, size_t ws_size,
                              hipStream_t stream) {
    const float* in1  = (const float*)d_in[0];  // input1  (1,3,H,W)
    const float* in2  = (const float*)d_in[1];  // input2  (1,3,H,W)
    const float* prev = (const float*)d_in[2];  // prev_frame1 (3,H,W)
    const float* flow = (const float*)d_in[3];  // flow1   (1,2,H,W)
    const float* m10  = (const float*)d_in[4];  // mask1_0 (1,3,H,W)
    const float* ex   = (const float*)d_in[5];  // exclusive_mask1 (1,3,H,W)
    const float* fast = (const float*)d_in[6];  // fastdvdnet (1,3,H,W)
    float* out = (float*)d_out;

    float* partial = (float*)d_ws;  // NB floats; written unconditionally
    const double invN = 1.0 / (3.0 * (double)HW);  // both means over B*C*H*W

    dim3 grid(NBX, NBY);
    fused_loss_kernel<<<grid, 256, 0, stream>>>(in1, in2, prev, flow, m10, ex,
                                                fast, partial);
    reduce_kernel<<<1, 256, 0, stream>>>(partial, out, invN);
}